// Round 1
// baseline (546.374 us; speedup 1.0000x reference)
//
#include <hip/hip_runtime.h>
#include <math.h>

// Problem constants: B=4 graphs, N=256 nodes/graph (128+128), F=256, L=3 layers.
#define FDIM   256
#define NNODE  1024      // B * N
#define NGR    4
#define LDS_PAD 68       // 64 + 4 pad: float4-aligned rows, modest bank conflicts

// ---------------------------------------------------------------- pack x ----
// x[node, f] ; node = b*256 + nl ; nl<128 -> desc0[b,f,nl] else desc1[b,f,nl-128]
__global__ void k_pack(const float* __restrict__ d0, const float* __restrict__ d1,
                       float* __restrict__ x) {
    int idx  = blockIdx.x * 256 + threadIdx.x;    // 262144 total
    int node = idx >> 8, f = idx & 255;
    int b = node >> 8, nl = node & 255;
    float v = (nl < 128) ? d0[b * 32768 + f * 128 + nl]
                         : d1[b * 32768 + f * 128 + (nl - 128)];
    x[idx] = v;
}

// ------------------------------------------------------------- H = x @ W ----
// grid (4 n-tiles, 16 m-tiles, 2 relations), block 256. C[r][n][e], W[r][f][e].
__global__ __launch_bounds__(256) void k_gemm_h(const float* __restrict__ x,
                                                const float* __restrict__ W,
                                                float* __restrict__ H) {
    const int r = blockIdx.z;
    const float* Bg = W + r * 65536;
    float* C = H + r * 262144;
    __shared__ float As[32 * LDS_PAD];
    __shared__ float Bs[32 * LDS_PAD];
    const int tid = threadIdx.x;
    const int tx = tid & 15, ty = tid >> 4;
    const int m0 = blockIdx.y * 64, n0 = blockIdx.x * 64;
    float acc[4][4] = {};
    for (int k0 = 0; k0 < 256; k0 += 32) {
        {   // A tile: 64 rows x 32 k, lanes along k (coalesced 128B)
            int kl = tid & 31, ml = tid >> 5;
            #pragma unroll
            for (int mi = 0; mi < 8; ++mi) {
                int m = mi * 8 + ml;
                As[kl * LDS_PAD + m] = x[(m0 + m) * 256 + k0 + kl];
            }
            // B tile: 32 k x 64 n, lanes along n (coalesced 256B)
            int nl = tid & 63, kl4 = tid >> 6;
            #pragma unroll
            for (int ki = 0; ki < 8; ++ki) {
                int k = ki * 4 + kl4;
                Bs[k * LDS_PAD + nl] = Bg[(k0 + k) * 256 + n0 + nl];
            }
        }
        __syncthreads();
        #pragma unroll 8
        for (int k = 0; k < 32; ++k) {
            float4 a4 = *(const float4*)&As[k * LDS_PAD + ty * 4];
            float4 b4 = *(const float4*)&Bs[k * LDS_PAD + tx * 4];
            float a[4] = {a4.x, a4.y, a4.z, a4.w};
            float b[4] = {b4.x, b4.y, b4.z, b4.w};
            #pragma unroll
            for (int i = 0; i < 4; ++i)
                #pragma unroll
                for (int j = 0; j < 4; ++j) acc[i][j] += a[i] * b[j];
        }
        __syncthreads();
    }
    #pragma unroll
    for (int i = 0; i < 4; ++i) {
        float4 o = {acc[i][0], acc[i][1], acc[i][2], acc[i][3]};
        *(float4*)&C[(m0 + ty * 4 + i) * 256 + n0 + tx * 4] = o;
    }
}

// ------------------------------------------------- qs/ks = H . q , H . k ----
// one wave per (r,node) row; 4 waves/block; 512 blocks.
__global__ void k_qsks(const float* __restrict__ H, const float* __restrict__ q,
                       const float* __restrict__ kk, float* __restrict__ qs,
                       float* __restrict__ ks) {
    int row  = blockIdx.x * 4 + (threadIdx.x >> 6);   // 0..2047 = r*1024+node
    int lane = threadIdx.x & 63;
    float4 h4 = *(const float4*)&H[row * 256 + lane * 4];
    float4 q4 = *(const float4*)&q[lane * 4];
    float4 k4 = *(const float4*)&kk[lane * 4];
    float sq = h4.x * q4.x + h4.y * q4.y + h4.z * q4.z + h4.w * q4.w;
    float sk = h4.x * k4.x + h4.y * k4.y + h4.z * k4.z + h4.w * k4.w;
    #pragma unroll
    for (int off = 32; off; off >>= 1) {
        sq += __shfl_xor(sq, off);
        sk += __shfl_xor(sk, off);
    }
    if (lane == 0) { qs[row] = sq; ks[row] = sk; }
}

// ----------------------------------------------------- alpha rows (softmax) -
// one wave per dst node; alpha[dst_global][s_local] normalized, self=0.
__global__ void k_alpha(const float* __restrict__ qs, const float* __restrict__ ks,
                        float* __restrict__ alpha) {
    int row  = blockIdx.x * 4 + (threadIdx.x >> 6);   // 0..1023 global dst
    int lane = threadIdx.x & 63;
    int g = row >> 8, dl = row & 255, a = (row >> 7) & 1;
    int s0  = lane * 4;
    int grp = s0 >> 7;                 // 4 contiguous s never cross the 128 split
    int t   = (grp == a) ? 0 : 1;
    float qv  = qs[t * 1024 + row];
    float4 kv = *(const float4*)&ks[t * 1024 + g * 256 + s0];
    float l[4] = {qv + kv.x, qv + kv.y, qv + kv.z, qv + kv.w};
    float mx = -1e30f;
    #pragma unroll
    for (int j = 0; j < 4; ++j) {
        l[j] = (l[j] >= 0.f) ? l[j] : 0.2f * l[j];     // leaky_relu 0.2
        if (s0 + j == dl) l[j] = -1e30f;               // exclude self-loop
        mx = fmaxf(mx, l[j]);
    }
    #pragma unroll
    for (int off = 32; off; off >>= 1) mx = fmaxf(mx, __shfl_xor(mx, off));
    float e[4]; float s = 0.f;
    #pragma unroll
    for (int j = 0; j < 4; ++j) { e[j] = __expf(l[j] - mx); s += e[j]; }
    #pragma unroll
    for (int off = 32; off; off >>= 1) s += __shfl_xor(s, off);
    float inv = 1.f / (s + 1e-16f);
    float4 o = {e[0] * inv, e[1] * inv, e[2] * inv, e[3] * inv};
    *(float4*)&alpha[row * 256 + s0] = o;
}

// ---------------------------- msg1 = relu(alpha @ H_sel + conv_b) -----------
// grid (4 n-tiles, 16 m-tiles). B rows picked from H[t][g*256+k]; k-tile (32)
// never crosses the 128 group split, so t is tile-uniform.
__global__ __launch_bounds__(256) void k_gemm_attn(const float* __restrict__ alpha,
                                                   const float* __restrict__ H,
                                                   const float* __restrict__ cb,
                                                   float* __restrict__ msg1) {
    __shared__ float As[32 * LDS_PAD];
    __shared__ float Bs[32 * LDS_PAD];
    const int tid = threadIdx.x;
    const int tx = tid & 15, ty = tid >> 4;
    const int m0 = blockIdx.y * 64, n0 = blockIdx.x * 64;
    const int g = m0 >> 8, a = (m0 >> 7) & 1;
    float acc[4][4] = {};
    for (int k0 = 0; k0 < 256; k0 += 32) {
        const int t = (((k0 >> 7) & 1) == a) ? 0 : 1;
        const float* Bg = H + t * 262144 + g * 65536;   // rows = local src k
        {
            int kl = tid & 31, ml = tid >> 5;
            #pragma unroll
            for (int mi = 0; mi < 8; ++mi) {
                int m = mi * 8 + ml;
                As[kl * LDS_PAD + m] = alpha[(m0 + m) * 256 + k0 + kl];
            }
            int nl = tid & 63, kl4 = tid >> 6;
            #pragma unroll
            for (int ki = 0; ki < 8; ++ki) {
                int k = ki * 4 + kl4;
                Bs[k * LDS_PAD + nl] = Bg[(k0 + k) * 256 + n0 + nl];
            }
        }
        __syncthreads();
        #pragma unroll 8
        for (int k = 0; k < 32; ++k) {
            float4 a4 = *(const float4*)&As[k * LDS_PAD + ty * 4];
            float4 b4 = *(const float4*)&Bs[k * LDS_PAD + tx * 4];
            float aa[4] = {a4.x, a4.y, a4.z, a4.w};
            float bb[4] = {b4.x, b4.y, b4.z, b4.w};
            #pragma unroll
            for (int i = 0; i < 4; ++i)
                #pragma unroll
                for (int j = 0; j < 4; ++j) acc[i][j] += aa[i] * bb[j];
        }
        __syncthreads();
    }
    #pragma unroll
    for (int i = 0; i < 4; ++i) {
        float4 o;
        o.x = fmaxf(acc[i][0] + cb[n0 + tx * 4 + 0], 0.f);
        o.y = fmaxf(acc[i][1] + cb[n0 + tx * 4 + 1], 0.f);
        o.z = fmaxf(acc[i][2] + cb[n0 + tx * 4 + 2], 0.f);
        o.w = fmaxf(acc[i][3] + cb[n0 + tx * 4 + 3], 0.f);
        *(float4*)&msg1[(m0 + ty * 4 + i) * 256 + n0 + tx * 4] = o;
    }
}

// ------------------- msg2 = concat(x,msg1) @ lin_w^T + lin_b ----------------
// K=512 (k<256 from x, else msg1). lin_w is [256 out][512 in] -> transposed
// staging into Bs[k][n].
__global__ __launch_bounds__(256) void k_gemm_lin(const float* __restrict__ x,
                                                  const float* __restrict__ msg1,
                                                  const float* __restrict__ lw,
                                                  const float* __restrict__ lb,
                                                  float* __restrict__ msg2) {
    __shared__ float As[32 * LDS_PAD];
    __shared__ float Bs[32 * LDS_PAD];
    const int tid = threadIdx.x;
    const int tx = tid & 15, ty = tid >> 4;
    const int m0 = blockIdx.y * 64, n0 = blockIdx.x * 64;
    float acc[4][4] = {};
    for (int k0 = 0; k0 < 512; k0 += 32) {
        const float* Ag = (k0 < 256) ? (x + k0) : (msg1 + (k0 - 256));
        {
            int kl = tid & 31, ml = tid >> 5;
            #pragma unroll
            for (int mi = 0; mi < 8; ++mi) {
                int m = mi * 8 + ml;
                As[kl * LDS_PAD + m] = Ag[(m0 + m) * 256 + kl];
            }
            // B: lanes along k of lin_w rows (coalesced 128B); Bs[k][n]
            int kl2 = tid & 31, nl8 = tid >> 5;
            #pragma unroll
            for (int ni = 0; ni < 8; ++ni) {
                int n = ni * 8 + nl8;
                Bs[kl2 * LDS_PAD + n] = lw[(n0 + n) * 512 + k0 + kl2];
            }
        }
        __syncthreads();
        #pragma unroll 8
        for (int k = 0; k < 32; ++k) {
            float4 a4 = *(const float4*)&As[k * LDS_PAD + ty * 4];
            float4 b4 = *(const float4*)&Bs[k * LDS_PAD + tx * 4];
            float aa[4] = {a4.x, a4.y, a4.z, a4.w};
            float bb[4] = {b4.x, b4.y, b4.z, b4.w};
            #pragma unroll
            for (int i = 0; i < 4; ++i)
                #pragma unroll
                for (int j = 0; j < 4; ++j) acc[i][j] += aa[i] * bb[j];
        }
        __syncthreads();
    }
    #pragma unroll
    for (int i = 0; i < 4; ++i) {
        float4 o;
        o.x = acc[i][0] + lb[n0 + tx * 4 + 0];
        o.y = acc[i][1] + lb[n0 + tx * 4 + 1];
        o.z = acc[i][2] + lb[n0 + tx * 4 + 2];
        o.w = acc[i][3] + lb[n0 + tx * 4 + 3];
        *(float4*)&msg2[(m0 + ty * 4 + i) * 256 + n0 + tx * 4] = o;
    }
}

// -------------------------------- BN partial sums (16 blocks x 64 rows) -----
__global__ void k_bnstat(const float* __restrict__ msg2, float* __restrict__ sums,
                         float* __restrict__ sumsq) {
    int b = blockIdx.x, t = threadIdx.x;       // t = column
    float s1 = 0.f, s2 = 0.f;
    #pragma unroll 4
    for (int r = 0; r < 64; ++r) {
        float v = msg2[(b * 64 + r) * 256 + t];
        s1 += v; s2 += v * v;
    }
    sums[b * 256 + t] = s1;
    sumsq[b * 256 + t] = s2;
}

// ---------------- x += bn_w*(msg2-mu)/sqrt(var+eps) + bn_b ------------------
__global__ void k_bnapply(const float* __restrict__ msg2, const float* __restrict__ sums,
                          const float* __restrict__ sumsq, const float* __restrict__ bw,
                          const float* __restrict__ bb, float* __restrict__ x) {
    int b = blockIdx.x, t = threadIdx.x;
    float s1 = 0.f, s2 = 0.f;
    #pragma unroll
    for (int i = 0; i < 16; ++i) { s1 += sums[i * 256 + t]; s2 += sumsq[i * 256 + t]; }
    float mu  = s1 * (1.f / 1024.f);
    float var = s2 * (1.f / 1024.f) - mu * mu;        // biased, as reference
    float rstd  = rsqrtf(var + 1e-5f);
    float scale = bw[t] * rstd;
    float shift = bb[t] - mu * scale;
    #pragma unroll 4
    for (int r = 0; r < 64; ++r) {
        int idx = (b * 64 + r) * 256 + t;
        x[idx] += msg2[idx] * scale + shift;
    }
}

// ------------------------------------------------------------- unpack -------
// out0[b,f,n] = x[b*256+n, f] ; out1[b,f,n] = x[b*256+128+n, f]
__global__ void k_unpack(const float* __restrict__ x, float* __restrict__ out) {
    int idx = blockIdx.x * 256 + threadIdx.x;          // 262144
    int half = (idx >= 131072) ? 1 : 0;
    int j = idx - half * 131072;
    int b = j >> 15, rem = j & 32767;
    int f = rem >> 7, n = rem & 127;
    int node = b * 256 + half * 128 + n;
    out[idx] = x[node * 256 + f];
}

// ----------------------------------------------------------------------------
extern "C" void kernel_launch(void* const* d_in, const int* in_sizes, int n_in,
                              void* d_out, int out_size, void* d_ws, size_t ws_size,
                              hipStream_t stream) {
    const float* desc0  = (const float*)d_in[0];
    const float* desc1  = (const float*)d_in[1];
    const float* conv_w = (const float*)d_in[2];   // [3,2,256,256]
    const float* conv_q = (const float*)d_in[3];   // [3,256]
    const float* conv_k = (const float*)d_in[4];
    const float* conv_b = (const float*)d_in[5];
    const float* lin_w  = (const float*)d_in[6];   // [3,256,512]
    const float* lin_b  = (const float*)d_in[7];
    const float* bn_w   = (const float*)d_in[8];
    const float* bn_b   = (const float*)d_in[9];
    float* out = (float*)d_out;

    float* ws = (float*)d_ws;
    float* x     = ws;                 // 262144
    float* H     = x + 262144;         // 2*262144
    float* qs    = H + 524288;         // 2048
    float* ks    = qs + 2048;          // 2048
    float* alpha = ks + 2048;          // 262144
    float* msg1  = alpha + 262144;     // 262144
    float* msg2  = msg1 + 262144;      // 262144
    float* sums  = msg2 + 262144;      // 4096
    float* sumsq = sums + 4096;        // 4096

    k_pack<<<1024, 256, 0, stream>>>(desc0, desc1, x);

    for (int i = 0; i < 3; ++i) {
        const float* cw = conv_w + i * 131072;
        const float* cq = conv_q + i * 256;
        const float* ck = conv_k + i * 256;
        const float* cb = conv_b + i * 256;
        const float* lw = lin_w + i * 131072;
        const float* lb = lin_b + i * 256;
        const float* bw = bn_w + i * 256;
        const float* bb = bn_b + i * 256;

        k_gemm_h<<<dim3(4, 16, 2), 256, 0, stream>>>(x, cw, H);
        k_qsks<<<512, 256, 0, stream>>>(H, cq, ck, qs, ks);
        k_alpha<<<256, 256, 0, stream>>>(qs, ks, alpha);
        k_gemm_attn<<<dim3(4, 16), 256, 0, stream>>>(alpha, H, cb, msg1);
        k_gemm_lin<<<dim3(4, 16), 256, 0, stream>>>(x, msg1, lw, lb, msg2);
        k_bnstat<<<16, 256, 0, stream>>>(msg2, sums, sumsq);
        k_bnapply<<<16, 256, 0, stream>>>(msg2, sums, sumsq, bw, bb, x);
    }

    k_unpack<<<1024, 256, 0, stream>>>(x, out);
}

// Round 2
// 173.882 us; speedup vs baseline: 3.1422x; 3.1422x over previous
//
#include <hip/hip_runtime.h>
#include <math.h>

// B=4 graphs, N=256 nodes/graph (128+128), F=256, L=3 layers.
// All GEMMs via bf16 MFMA 16x16x32, one wave per 16x32 output tile, no LDS
// in the K-loop (operands L2-resident, 16B/lane contiguous frag loads).

typedef __attribute__((ext_vector_type(8))) short short8;   // 8 bf16 = 4 VGPRs
typedef __attribute__((ext_vector_type(4))) float f32x4;
typedef unsigned short u16;
typedef unsigned int   u32;

__device__ __forceinline__ u16 f2bf(float f) {
    union { float f; u32 u; } v; v.f = f;
    u32 r = v.u + 0x7fffu + ((v.u >> 16) & 1u);     // RNE
    return (u16)(r >> 16);
}
__device__ __forceinline__ float bf2f(u16 h) {
    union { u32 u; float f; } v; v.u = ((u32)h) << 16;
    return v.f;
}
__device__ __forceinline__ short8 ld8(const u16* p) {
    return __builtin_bit_cast(short8, *(const int4*)p);
}

// ---------------------------------------------------------------- pack x ----
__global__ void k_pack(const float* __restrict__ d0, const float* __restrict__ d1,
                       float* __restrict__ x, u16* __restrict__ xb) {
    int idx  = blockIdx.x * 256 + threadIdx.x;    // 262144
    int node = idx >> 8, f = idx & 255;
    int b = node >> 8, nl = node & 255;
    float v = (nl < 128) ? d0[b * 32768 + f * 128 + nl]
                         : d1[b * 32768 + f * 128 + (nl - 128)];
    x[idx] = v;
    xb[idx] = f2bf(v);
}

// ------------------------------ weight prep: Wt (transposed) + lwb casts ----
// Wt[layer][r][e][f] = conv_w[layer][r][f][e];  lwb = bf16(lin_w) (layout kept)
__global__ void k_prep(const float* __restrict__ conv_w, const float* __restrict__ lin_w,
                       u16* __restrict__ Wt, u16* __restrict__ lwb) {
    int o = blockIdx.x * 256 + threadIdx.x;       // 786432
    if (o < 393216) {
        int mat = o >> 16, rem = o & 65535;       // 6 matrices of 256x256
        int e = rem >> 8, f = rem & 255;
        Wt[o] = f2bf(conv_w[mat * 65536 + f * 256 + e]);
    } else {
        int o2 = o - 393216;
        lwb[o2] = f2bf(lin_w[o2]);
    }
}

// ----------------------------------------- Ht[r][e][node] = (xb @ Wt[r])^T --
// grid (8 e-tiles, 64 m-tiles, 2 rel), 64 threads (1 wave). A=xb[m][k], B=Wt[e][k].
__global__ __launch_bounds__(64) void k_gemm_h(const u16* __restrict__ xb,
                                               const u16* __restrict__ Wt,
                                               u16* __restrict__ Ht) {
    const int lane = threadIdx.x;
    const int row = lane & 15, kg = lane >> 4;
    const int n0 = blockIdx.x * 32;               // e
    const int m0 = blockIdx.y * 16;               // node
    const int r  = blockIdx.z;
    const u16* A = xb + (m0 + row) * 256 + kg * 8;
    const u16* B = Wt + r * 65536 + (n0 + row) * 256 + kg * 8;
    f32x4 acc0 = {0.f, 0.f, 0.f, 0.f}, acc1 = {0.f, 0.f, 0.f, 0.f};
    #pragma unroll
    for (int k0 = 0; k0 < 256; k0 += 32) {
        short8 a  = ld8(A + k0);
        short8 b0 = ld8(B + k0);
        short8 b1 = ld8(B + 16 * 256 + k0);
        acc0 = __builtin_amdgcn_mfma_f32_16x16x32_bf16(a, b0, acc0, 0, 0, 0);
        acc1 = __builtin_amdgcn_mfma_f32_16x16x32_bf16(a, b1, acc1, 0, 0, 0);
    }
    // C/D: col = lane&15 (-> e), rows = kg*4+reg (-> node). Write transposed.
    u16* O = Ht + (r * 256 + n0 + row) * 1024 + m0 + kg * 4;
    ushort4 o0, o1;
    o0.x = f2bf(acc0[0]); o0.y = f2bf(acc0[1]); o0.z = f2bf(acc0[2]); o0.w = f2bf(acc0[3]);
    o1.x = f2bf(acc1[0]); o1.y = f2bf(acc1[1]); o1.z = f2bf(acc1[2]); o1.w = f2bf(acc1[3]);
    *(ushort4*)O = o0;
    *(ushort4*)(O + 16 * 1024) = o1;
}

// ------------------- qs/ks partial dots over 64-e chunks (coalesced nodes) --
// grid (8 = t*4+chunk, 4 node-blocks) x 256 thr.
__global__ void k_qsks(const u16* __restrict__ Ht, const float* __restrict__ cq,
                       const float* __restrict__ ck, float* __restrict__ qpart,
                       float* __restrict__ kpart) {
    const int node = blockIdx.y * 256 + threadIdx.x;
    const int t = blockIdx.x >> 2, c = blockIdx.x & 3;
    const u16* hp = Ht + t * 262144 + node;
    float sq = 0.f, sk = 0.f;
    #pragma unroll 8
    for (int e = c * 64; e < c * 64 + 64; ++e) {
        float v = bf2f(hp[e * 1024]);
        sq += v * cq[e];
        sk += v * ck[e];
    }
    qpart[blockIdx.x * 1024 + node] = sq;
    kpart[blockIdx.x * 1024 + node] = sk;
}

// ------------------------- alpha rows: leaky-relu + softmax, bf16 output ----
__global__ void k_alpha(const float* __restrict__ qpart, const float* __restrict__ kpart,
                        u16* __restrict__ alphab) {
    int rowg = blockIdx.x * 4 + (threadIdx.x >> 6);   // global dst 0..1023
    int lane = threadIdx.x & 63;
    int g = rowg >> 8, dl = rowg & 255, a = (rowg >> 7) & 1;
    int s0 = lane * 4;
    int t = ((s0 >> 7) == a) ? 0 : 1;                 // 4 srcs never cross 128 split
    float qv = 0.f;
    float kx = 0.f, ky = 0.f, kz = 0.f, kw = 0.f;
    #pragma unroll
    for (int c = 0; c < 4; ++c) {
        qv += qpart[(t * 4 + c) * 1024 + rowg];
        float4 k4 = *(const float4*)&kpart[(t * 4 + c) * 1024 + g * 256 + s0];
        kx += k4.x; ky += k4.y; kz += k4.z; kw += k4.w;
    }
    float l[4] = {qv + kx, qv + ky, qv + kz, qv + kw};
    float mx = -1e30f;
    #pragma unroll
    for (int j = 0; j < 4; ++j) {
        l[j] = (l[j] >= 0.f) ? l[j] : 0.2f * l[j];    // leaky_relu 0.2
        if (s0 + j == dl) l[j] = -1e30f;              // no self-loop
        mx = fmaxf(mx, l[j]);
    }
    #pragma unroll
    for (int off = 32; off; off >>= 1) mx = fmaxf(mx, __shfl_xor(mx, off));
    float e[4]; float s = 0.f;
    #pragma unroll
    for (int j = 0; j < 4; ++j) { e[j] = __expf(l[j] - mx); s += e[j]; }
    #pragma unroll
    for (int off = 32; off; off >>= 1) s += __shfl_xor(s, off);
    float inv = 1.f / (s + 1e-16f);
    ushort4 o;
    o.x = f2bf(e[0] * inv); o.y = f2bf(e[1] * inv);
    o.z = f2bf(e[2] * inv); o.w = f2bf(e[3] * inv);
    *(ushort4*)(alphab + rowg * 256 + s0) = o;
}

// -------------------- msg1b[node][e] = relu(alpha @ H_sel + cb), bf16 -------
// grid (8 e-tiles, 64 dst-tiles), 1 wave. A=alphab[dst][src], B=Ht[t][e][src].
__global__ __launch_bounds__(64) void k_gemm_attn(const u16* __restrict__ alphab,
                                                  const u16* __restrict__ Ht,
                                                  const float* __restrict__ cb,
                                                  u16* __restrict__ msg1b) {
    __shared__ float T[16 * 36];
    const int lane = threadIdx.x;
    const int row = lane & 15, kg = lane >> 4;
    const int n0 = blockIdx.x * 32;
    const int m0 = blockIdx.y * 16;
    const int g = m0 >> 8, a = (m0 >> 7) & 1;
    const u16* A = alphab + (m0 + row) * 256 + kg * 8;
    f32x4 acc0 = {0.f, 0.f, 0.f, 0.f}, acc1 = {0.f, 0.f, 0.f, 0.f};
    #pragma unroll
    for (int k0 = 0; k0 < 256; k0 += 32) {
        const int t = (((k0 >> 7) & 1) == a) ? 0 : 1;   // k-tile uniform relation
        const u16* B = Ht + t * 262144 + (n0 + row) * 1024 + g * 256 + k0 + kg * 8;
        short8 av = ld8(A + k0);
        short8 b0 = ld8(B);
        short8 b1 = ld8(B + 16 * 1024);
        acc0 = __builtin_amdgcn_mfma_f32_16x16x32_bf16(av, b0, acc0, 0, 0, 0);
        acc1 = __builtin_amdgcn_mfma_f32_16x16x32_bf16(av, b1, acc1, 0, 0, 0);
    }
    #pragma unroll
    for (int c = 0; c < 4; ++c) {
        T[(kg * 4 + c) * 36 + row]      = fmaxf(acc0[c] + cb[n0 + row], 0.f);
        T[(kg * 4 + c) * 36 + 16 + row] = fmaxf(acc1[c] + cb[n0 + 16 + row], 0.f);
    }
    __syncthreads();
    u32 p[4];
    #pragma unroll
    for (int j = 0; j < 4; ++j) {
        u32 lo = f2bf(T[row * 36 + kg * 8 + 2 * j]);
        u32 hi = f2bf(T[row * 36 + kg * 8 + 2 * j + 1]);
        p[j] = lo | (hi << 16);
    }
    uint4 ov = {p[0], p[1], p[2], p[3]};
    *(uint4*)(msg1b + (m0 + row) * 256 + n0 + kg * 8) = ov;
}

// ----------------- msg2[node][out] = concat(xb,msg1b) @ lwb^T + lb, fp32 ----
// grid (8 n-tiles, 64 m-tiles), 1 wave. K=512; lwb is [out][in] = B^T already.
__global__ __launch_bounds__(64) void k_gemm_lin(const u16* __restrict__ xb,
                                                 const u16* __restrict__ msg1b,
                                                 const u16* __restrict__ lwb,
                                                 const float* __restrict__ lb,
                                                 float* __restrict__ msg2) {
    __shared__ float T[16 * 36];
    const int lane = threadIdx.x;
    const int row = lane & 15, kg = lane >> 4;
    const int n0 = blockIdx.x * 32;
    const int m0 = blockIdx.y * 16;
    const u16* A0 = xb    + (m0 + row) * 256 + kg * 8;
    const u16* A1 = msg1b + (m0 + row) * 256 + kg * 8;
    const u16* B  = lwb + (n0 + row) * 512 + kg * 8;
    f32x4 acc0 = {0.f, 0.f, 0.f, 0.f}, acc1 = {0.f, 0.f, 0.f, 0.f};
    #pragma unroll
    for (int k0 = 0; k0 < 512; k0 += 32) {
        short8 av = (k0 < 256) ? ld8(A0 + k0) : ld8(A1 + (k0 - 256));
        short8 b0 = ld8(B + k0);
        short8 b1 = ld8(B + 16 * 512 + k0);
        acc0 = __builtin_amdgcn_mfma_f32_16x16x32_bf16(av, b0, acc0, 0, 0, 0);
        acc1 = __builtin_amdgcn_mfma_f32_16x16x32_bf16(av, b1, acc1, 0, 0, 0);
    }
    #pragma unroll
    for (int c = 0; c < 4; ++c) {
        T[(kg * 4 + c) * 36 + row]      = acc0[c] + lb[n0 + row];
        T[(kg * 4 + c) * 36 + 16 + row] = acc1[c] + lb[n0 + 16 + row];
    }
    __syncthreads();
    float4 v0, v1;
    v0.x = T[row * 36 + kg * 8 + 0]; v0.y = T[row * 36 + kg * 8 + 1];
    v0.z = T[row * 36 + kg * 8 + 2]; v0.w = T[row * 36 + kg * 8 + 3];
    v1.x = T[row * 36 + kg * 8 + 4]; v1.y = T[row * 36 + kg * 8 + 5];
    v1.z = T[row * 36 + kg * 8 + 6]; v1.w = T[row * 36 + kg * 8 + 7];
    float* O = msg2 + (m0 + row) * 256 + n0 + kg * 8;
    *(float4*)O = v0;
    *(float4*)(O + 4) = v1;
}

// ------------------------------------------- BN partial sums (32 x 32 rows) -
__global__ void k_bnstat(const float* __restrict__ msg2, float* __restrict__ sums,
                         float* __restrict__ sumsq) {
    int b = blockIdx.x, t = threadIdx.x;
    float s1 = 0.f, s2 = 0.f;
    #pragma unroll 8
    for (int r = 0; r < 32; ++r) {
        float v = msg2[(b * 32 + r) * 256 + t];
        s1 += v; s2 += v * v;
    }
    sums[b * 256 + t] = s1;
    sumsq[b * 256 + t] = s2;
}

// ---------------- x += bn_w*(msg2-mu)/sqrt(var+eps) + bn_b ; refresh xb -----
__global__ void k_bnapply(const float* __restrict__ msg2, const float* __restrict__ sums,
                          const float* __restrict__ sumsq, const float* __restrict__ bw,
                          const float* __restrict__ bb, float* __restrict__ x,
                          u16* __restrict__ xb) {
    int b = blockIdx.x, t = threadIdx.x;
    float s1 = 0.f, s2 = 0.f;
    #pragma unroll
    for (int i = 0; i < 32; ++i) { s1 += sums[i * 256 + t]; s2 += sumsq[i * 256 + t]; }
    float mu  = s1 * (1.f / 1024.f);
    float var = s2 * (1.f / 1024.f) - mu * mu;        // biased, as reference
    float scale = bw[t] * rsqrtf(var + 1e-5f);
    float shift = bb[t] - mu * scale;
    #pragma unroll 4
    for (int r = 0; r < 32; ++r) {
        int idx = (b * 32 + r) * 256 + t;
        float nv = x[idx] + msg2[idx] * scale + shift;
        x[idx] = nv;
        xb[idx] = f2bf(nv);
    }
}

// ------------------------------------------------------------- unpack -------
__global__ void k_unpack(const float* __restrict__ x, float* __restrict__ out) {
    int idx = blockIdx.x * 256 + threadIdx.x;          // 262144
    int half = (idx >= 131072) ? 1 : 0;
    int j = idx - half * 131072;
    int b = j >> 15, rem = j & 32767;
    int f = rem >> 7, n = rem & 127;
    int node = b * 256 + half * 128 + n;
    out[idx] = x[node * 256 + f];
}

// ----------------------------------------------------------------------------
extern "C" void kernel_launch(void* const* d_in, const int* in_sizes, int n_in,
                              void* d_out, int out_size, void* d_ws, size_t ws_size,
                              hipStream_t stream) {
    const float* desc0  = (const float*)d_in[0];
    const float* desc1  = (const float*)d_in[1];
    const float* conv_w = (const float*)d_in[2];   // [3,2,256,256]
    const float* conv_q = (const float*)d_in[3];   // [3,256]
    const float* conv_k = (const float*)d_in[4];
    const float* conv_b = (const float*)d_in[5];
    const float* lin_w  = (const float*)d_in[6];   // [3,256,512]
    const float* lin_b  = (const float*)d_in[7];
    const float* bn_w   = (const float*)d_in[8];
    const float* bn_b   = (const float*)d_in[9];
    float* out = (float*)d_out;

    char* w = (char*)d_ws;
    float* x      = (float*)w; w += 1048576;       // [1024][256] fp32
    u16*   xb     = (u16*)w;   w += 524288;        // [1024][256] bf16
    u16*   Wt     = (u16*)w;   w += 786432;        // [3][2][256 e][256 f] bf16
    u16*   lwb    = (u16*)w;   w += 786432;        // [3][256][512] bf16
    u16*   Ht     = (u16*)w;   w += 1048576;       // [2][256 e][1024 node] bf16
    float* qpart  = (float*)w; w += 32768;         // [8][1024]
    float* kpart  = (float*)w; w += 32768;         // [8][1024]
    u16*   alphab = (u16*)w;   w += 524288;        // [1024][256] bf16
    u16*   msg1b  = (u16*)w;   w += 524288;        // [1024][256] bf16
    float* msg2   = (float*)w; w += 1048576;       // [1024][256] fp32
    float* sums   = (float*)w; w += 32768;         // [32][256]
    float* sumsq  = (float*)w; w += 32768;

    k_pack<<<1024, 256, 0, stream>>>(desc0, desc1, x, xb);
    k_prep<<<3072, 256, 0, stream>>>(conv_w, lin_w, Wt, lwb);

    for (int i = 0; i < 3; ++i) {
        const u16*   cwt = Wt + i * 131072;
        const u16*   lwp = lwb + i * 131072;
        const float* cq = conv_q + i * 256;
        const float* ck = conv_k + i * 256;
        const float* cb = conv_b + i * 256;
        const float* lb = lin_b + i * 256;
        const float* bw = bn_w + i * 256;
        const float* bb = bn_b + i * 256;

        k_gemm_h<<<dim3(8, 64, 2), 64, 0, stream>>>(xb, cwt, Ht);
        k_qsks<<<dim3(8, 4), 256, 0, stream>>>(Ht, cq, ck, qpart, kpart);
        k_alpha<<<256, 256, 0, stream>>>(qpart, kpart, alphab);
        k_gemm_attn<<<dim3(8, 64), 64, 0, stream>>>(alphab, Ht, cb, msg1b);
        k_gemm_lin<<<dim3(8, 64), 64, 0, stream>>>(xb, msg1b, lwp, lb, msg2);
        k_bnstat<<<32, 256, 0, stream>>>(msg2, sums, sumsq);
        k_bnapply<<<32, 256, 0, stream>>>(msg2, sums, sumsq, bw, bb, x, xb);
    }

    k_unpack<<<1024, 256, 0, stream>>>(x, out);
}